// Round 13
// baseline (208.461 us; speedup 1.0000x reference)
//
#include <hip/hip_runtime.h>
#include <hip/hip_bf16.h>
#include <cstdint>
#include <cstddef>

typedef __bf16 bf16;
typedef __attribute__((ext_vector_type(8))) __bf16 bf16x8;
typedef __attribute__((ext_vector_type(4))) __bf16 bf16x4v;
typedef __attribute__((ext_vector_type(4))) float f32x4;

#define NB 2
#define NT 2048
#define NE 2048
#define NH 32
#define NHKV 8
#define ND 64
#define NBT (NB * NT)
#define NQKV 3072

__device__ __forceinline__ void gload_lds16(const void* g, void* l) {
  __builtin_amdgcn_global_load_lds(
      (const __attribute__((address_space(1))) unsigned int*)g,
      (__attribute__((address_space(3))) unsigned int*)l, 16, 0, 0);
}

// XOR swizzle for 128-byte LDS rows: spreads the 16-way bank conflict.
__device__ __forceinline__ int swz(int row, int byteoff) {
  return (row * 128 + byteoff) ^ ((row & 7) << 4);
}

// ---------------------------------------------------------------- prep kernel
// One fused launch: x->bf16 cvt, rope table, 4 weight transposes.
// Zones by blockIdx.x:  [0,1024) cvt | [1024,1280) table |
// [1280,5376) Wq^T | [5376,6400) Wk^T | [6400,7424) Wv^T | [7424,11520) Wo^T

__global__ __launch_bounds__(256)
void prep_kernel(const float* __restrict__ x, const float* __restrict__ Wq,
                 const float* __restrict__ Wk, const float* __restrict__ Wv,
                 const float* __restrict__ Wo, bf16* __restrict__ xb,
                 bf16* __restrict__ wqkv_t, bf16* __restrict__ wo_t,
                 float* __restrict__ tab) {
  const int bid = blockIdx.x, tid = threadIdx.x;

  if (bid < 1024) {  // x -> bf16, vectorized, grid-stride
    const int n4 = NBT * NE / 4;
    for (int i = bid * 256 + tid; i < n4; i += 1024 * 256) {
      const float4 v = ((const float4*)x)[i];
      bf16x4v o;
      o[0] = (bf16)v.x; o[1] = (bf16)v.y; o[2] = (bf16)v.z; o[3] = (bf16)v.w;
      ((bf16x4v*)xb)[i] = o;
    }
    return;
  }
  if (bid < 1280) {  // rope cos/sin table (65536 entries exactly)
    const int i = (bid - 1024) * 256 + tid;
    const int t = i >> 5, d = i & 31;
    const float inv = expf(-(float)d * 0.28782313662425574f);  // ln(10000)/32
    const float ang = (float)t * inv;
    tab[t * 64 + d] = cosf(ang);
    tab[t * 64 + 32 + d] = sinf(ang);
    return;
  }

  __shared__ float tile[32][33];
  const float* in;
  bf16* outp;
  int ncols, rowoff, gx, sub;
  if (bid < 5376)      { sub = bid - 1280; in = Wq; outp = wqkv_t; ncols = 2048; rowoff = 0;    gx = 64; }
  else if (bid < 6400) { sub = bid - 5376; in = Wk; outp = wqkv_t; ncols = 512;  rowoff = 2048; gx = 16; }
  else if (bid < 7424) { sub = bid - 6400; in = Wv; outp = wqkv_t; ncols = 512;  rowoff = 2560; gx = 16; }
  else                 { sub = bid - 7424; in = Wo; outp = wo_t;   ncols = 2048; rowoff = 0;    gx = 64; }
  const int c0 = (sub % gx) * 32, k0 = (sub / gx) * 32;
  const int tx = tid & 31, ty = tid >> 5;
#pragma unroll
  for (int j = 0; j < 4; ++j)
    tile[ty + j * 8][tx] = in[(size_t)(k0 + ty + j * 8) * ncols + c0 + tx];
  __syncthreads();
#pragma unroll
  for (int j = 0; j < 4; ++j)
    outp[(size_t)(rowoff + c0 + ty + j * 8) * 2048 + k0 + tx] = (bf16)tile[tx][ty + j * 8];
}

// ---------------------------------------------------------------- GEMM (ring-3, never-drain, T2-swizzled)
// C[M][N] = A[M][K] * Bt[N][K]^T ; 128x128 tile, BK=32, 4 waves.
// Ring-3 LDS (48 KB -> 3 blocks/CU TLP) + prefetch distance 2 K-tiles +
// counted vmcnt(4) + ONE raw barrier per K-tile. T2 both-sides swizzle.
// ROPE epilogue: rotate (d,d+32) pairs for q/k heads (cols<2560), fold
// 0.125*log2(e) into Q (cols<2048), and write V panel (cols>=2560)
// TRANSPOSED into vt[b][hk][d][t].

template <typename CT, bool ROPE>
__global__ __launch_bounds__(256, 3)
void gemm_r3_kernel(const bf16* __restrict__ A, const bf16* __restrict__ Bt,
                    CT* __restrict__ C, int M, int N, int K,
                    const float* __restrict__ tab, bf16* __restrict__ vt) {
  __shared__ __align__(16) bf16 As[3][128 * 32];
  __shared__ __align__(16) bf16 Bs[3][128 * 32];
  const int tid = threadIdx.x;
  const int lane = tid & 63, wid = tid >> 6;
  const int wr = wid >> 1, wc = wid & 1;
  const int cpx = (int)gridDim.x >> 3;
  const int swzb = ((int)blockIdx.x & 7) * cpx + ((int)blockIdx.x >> 3);
  const int gx = N >> 7;
  const int bx = swzb % gx, by = swzb / gx;
  const int m0 = by * 128, n0 = bx * 128;
  const int srow = tid >> 2;                              // 0..63 staging row
  const int skoff = 8 * ((tid & 3) ^ ((tid >> 3) & 3));   // T2 source swizzle
  const bf16* ga = A + (size_t)(m0 + srow) * K + skoff;
  const bf16* gb = Bt + (size_t)(n0 + srow) * K + skoff;
  const int fr = lane & 15;
  const int fq = lane >> 4;
  const int fks = 8 * (fq ^ ((fr >> 1) & 3));             // T2 read swizzle
  const int NTK = K >> 5;
  f32x4 acc[4][4] = {};

#define STAGE_T(b, t)                                                   \
  do {                                                                  \
    const int kk = (t) * 32;                                            \
    gload_lds16(ga + kk, &As[b][tid * 8]);                              \
    gload_lds16(ga + kk + (size_t)64 * K, &As[b][2048 + tid * 8]);      \
    gload_lds16(gb + kk, &Bs[b][tid * 8]);                              \
    gload_lds16(gb + kk + (size_t)64 * K, &Bs[b][2048 + tid * 8]);      \
  } while (0)

  STAGE_T(0, 0);
  STAGE_T(1, 1);

  int bc = 0;
  for (int t = 0; t < NTK; ++t) {
    if (t + 1 < NTK) asm volatile("s_waitcnt vmcnt(4)" ::: "memory");
    else             asm volatile("s_waitcnt vmcnt(0)" ::: "memory");
    __builtin_amdgcn_s_barrier();

    bf16x8 af[4], bfr[4];
#pragma unroll
    for (int m = 0; m < 4; ++m)
      af[m] = *(const bf16x8*)&As[bc][(wr * 64 + m * 16 + fr) * 32 + fks];
#pragma unroll
    for (int n = 0; n < 4; ++n)
      bfr[n] = *(const bf16x8*)&Bs[bc][(wc * 64 + n * 16 + fr) * 32 + fks];

    if (t + 2 < NTK) {
      const int pb = (bc + 2 >= 3) ? bc - 1 : bc + 2;
      STAGE_T(pb, t + 2);
    }

    __builtin_amdgcn_s_setprio(1);
#pragma unroll
    for (int m = 0; m < 4; ++m)
#pragma unroll
      for (int n = 0; n < 4; ++n)
        acc[m][n] = __builtin_amdgcn_mfma_f32_16x16x32_bf16(af[m], bfr[n], acc[m][n], 0, 0, 0);
    __builtin_amdgcn_s_setprio(0);
    bc = (bc + 1 == 3) ? 0 : bc + 1;
  }
#undef STAGE_T

  const int colbase = n0 + wc * 64;

  if (ROPE && colbase >= 2560) {
    // V panel: write transposed into vt[b][hk][d][t].
    const int hk = (colbase - 2560) >> 6;
    const int bb = m0 >> 11;
    const int t0 = (m0 & (NT - 1)) + wr * 64 + fq * 4;
    bf16* vtp = vt + (size_t)(bb * NHKV + hk) * 64 * NT;
#pragma unroll
    for (int m = 0; m < 4; ++m) {
#pragma unroll
      for (int n = 0; n < 4; ++n) {
        const int d = n * 16 + fr;
        bf16x4v w;
        w[0] = (bf16)acc[m][n][0];
        w[1] = (bf16)acc[m][n][1];
        w[2] = (bf16)acc[m][n][2];
        w[3] = (bf16)acc[m][n][3];
        *(bf16x4v*)&vtp[(size_t)d * NT + t0 + m * 16] = w;
      }
    }
    return;
  }

  const bool do_rope = ROPE && colbase < 2560;
  const bool do_scale = ROPE && colbase < 2048;
  const float SCALE = 0.18033688011112042f;  // 0.125 * log2(e)
  const int orow0 = m0 + wr * 64 + fq * 4;
  const int ocol0 = colbase + fr;
#pragma unroll
  for (int m = 0; m < 4; ++m) {
#pragma unroll
    for (int j = 0; j < 4; ++j) {
      const int row = orow0 + m * 16 + j;
      float v0 = acc[m][0][j], v1 = acc[m][1][j], v2 = acc[m][2][j], v3 = acc[m][3][j];
      if (do_rope) {
        const int tt = row & (NT - 1);
        const float c0 = tab[tt * 64 + fr],      s0 = tab[tt * 64 + 32 + fr];
        const float c1 = tab[tt * 64 + 16 + fr], s1 = tab[tt * 64 + 48 + fr];
        const float a0 = v0, a2 = v2;
        v0 = a0 * c0 - a2 * s0;
        v2 = a2 * c0 + a0 * s0;
        const float a1 = v1, a3 = v3;
        v1 = a1 * c1 - a3 * s1;
        v3 = a3 * c1 + a1 * s1;
        if (do_scale) { v0 *= SCALE; v1 *= SCALE; v2 *= SCALE; v3 *= SCALE; }
      }
      CT* cp = &C[(size_t)row * N + ocol0];
      cp[0] = (CT)v0; cp[16] = (CT)v1; cp[32] = (CT)v2; cp[48] = (CT)v3;
    }
  }
}

// ---------------------------------------------------------------- attention
// Swapped-operand flash attention with CAUSAL LOAD-BALANCE FOLD.
// 64-row q-tiles (32 total). Block pidx handles the pair (pidx, 31-pidx)
// sequentially: phase A = q-tile pidx (pidx+1 kv-tiles), phase B = q-tile
// 31-pidx (32-pidx kv-tiles) -> EVERY block = exactly 33 tiles. Grid 1024 =
// 4 blocks/CU, all resident, uniform duration, zero tail (r12's 27% avg
// occupancy was the decaying-tail profile of 2..32-tile blocks).
// Per wave: 16 q rows per phase (single set). Ring-2 K/V LDS, per tile:
// vmcnt(0) -> barrier -> STAGE(next in flattened 33-tile kv sequence).
// K row-permuted in LDS (conflict-free kf). Q pre-scaled by 0.125*log2(e)
// in GEMM1. Softmax log2-domain, defer-max (T13), l via MFMA.
// __launch_bounds__(256,3): measured no-spill sweet spot (r8-r11 ladder).

__global__ __launch_bounds__(256, 3)
void attn_kernel(const bf16* __restrict__ qkv, const bf16* __restrict__ vt,
                 bf16* __restrict__ y) {
  const int bid = blockIdx.x;
  const int pidx = bid >> 6;         // pair index 0..15
  const int bh = bid & 63;
  const int b = bh >> 5, h = bh & 31, hk = h >> 2;
  const int q0A = pidx * 64;
  const int q0B = (31 - pidx) * 64;
  const int ntA = pidx + 1;          // phase-A kv tiles; total is always 33

  __shared__ __align__(16) bf16 Kb[2][4096], Vb[2][4096];

  const int tid = threadIdx.x;
  const int lane = tid & 63, wid = tid >> 6;
  const int ql = lane & 15;
  const int sub = lane >> 4;

  const int st_r = tid >> 3;
  const int kperm = 4 * (st_r >> 4) + 8 * ((st_r >> 2) & 3) + (st_r & 3);
  const int csw = ((tid & 7) ^ (st_r & 7)) * 8;
  const bf16* kgbase = qkv + (size_t)(b * NT + kperm) * NQKV + 2048 + hk * 64 + csw;
  const bf16* vgbase = vt + ((size_t)(b * NHKV + hk) * 64 + st_r) * NT + csw;

  auto STAGE = [&](int buf, int kv0) {
    const bf16* kg = kgbase + (size_t)kv0 * NQKV;
    gload_lds16(kg, Kb[buf] + tid * 8);
    gload_lds16(kg + (size_t)32 * NQKV, Kb[buf] + 2048 + tid * 8);
    const bf16* vg = vgbase + kv0;
    gload_lds16(vg, Vb[buf] + tid * 8);
    gload_lds16(vg + 32 * NT, Vb[buf] + 2048 + tid * 8);
  };

  // Q fragments for both phases (post-RoPE, pre-scaled): col=q=ql, k=d
  bf16x8 qfA[2], qfB[2];
  {
    const bf16* qp = qkv + (size_t)(b * NT + q0A + wid * 16 + ql) * NQKV + h * 64 + sub * 8;
    qfA[0] = *(const bf16x8*)qp;
    qfA[1] = *(const bf16x8*)(qp + 32);
    const bf16* qp2 = qkv + (size_t)(b * NT + q0B + wid * 16 + ql) * NQKV + h * 64 + sub * 8;
    qfB[0] = *(const bf16x8*)qp2;
    qfB[1] = *(const bf16x8*)(qp2 + 32);
  }

  bf16x8 ones8;
#pragma unroll
  for (int i = 0; i < 8; ++i) ones8[i] = (bf16)1.0f;

  f32x4 o[4] = {};
  f32x4 ol = {};                  // l accumulator via MFMA (all 4 elems equal)
  float m_s = -1e30f;

  auto FLUSH = [&](int q0) {
    const float inv = 1.0f / ol[0];
    bf16* yp = y + (size_t)(b * NT + q0 + wid * 16 + ql) * NE + h * 64 + sub * 4;
#pragma unroll
    for (int dt = 0; dt < 4; ++dt) {
      bf16x4v w;
      w[0] = (bf16)(o[dt][0] * inv);
      w[1] = (bf16)(o[dt][1] * inv);
      w[2] = (bf16)(o[dt][2] * inv);
      w[3] = (bf16)(o[dt][3] * inv);
      *(bf16x4v*)(yp + dt * 16) = w;
    }
  };

  STAGE(0, 0);

  for (int f = 0; f < 33; ++f) {
    const bool phB = (f >= ntA);
    const int kv0 = (phB ? f - ntA : f) * 64;
    const int bc = f & 1;
    asm volatile("s_waitcnt vmcnt(0)" ::: "memory");
    __builtin_amdgcn_s_barrier();
    if (f + 1 < 33) {
      const int nf = f + 1;
      const int nkv = (nf >= ntA ? nf - ntA : nf) * 64;
      STAGE(bc ^ 1, nkv);
    }

    const int qlo = (phB ? q0B : q0A) + wid * 16;

    // K fragments: LDS rows pre-permuted -> linear row n*16+ql read.
    bf16x8 kf[4][2];
#pragma unroll
    for (int n = 0; n < 4; ++n)
#pragma unroll
      for (int c = 0; c < 2; ++c)
        kf[n][c] = *(const bf16x8*)((const char*)Kb[bc] + swz(n * 16 + ql, c * 64 + sub * 16));
    bf16x8 vf[2][4];
#pragma unroll
    for (int kc = 0; kc < 2; ++kc)
#pragma unroll
      for (int dt = 0; dt < 4; ++dt)
        vf[kc][dt] = *(const bf16x8*)((const char*)Vb[bc] + swz(dt * 16 + ql, kc * 64 + sub * 16));

    const bf16x8 qf0 = phB ? qfB[0] : qfA[0];
    const bf16x8 qf1 = phB ? qfB[1] : qfA[1];

    f32x4 s[4] = {};
    __builtin_amdgcn_s_setprio(1);
#pragma unroll
    for (int n = 0; n < 4; ++n) {
      s[n] = __builtin_amdgcn_mfma_f32_16x16x32_bf16(kf[n][0], qf0, s[n], 0, 0, 0);
      s[n] = __builtin_amdgcn_mfma_f32_16x16x32_bf16(kf[n][1], qf1, s[n], 0, 0, 0);
    }
    __builtin_amdgcn_s_setprio(0);

    // lane holds S^T[kv = kv0+32(n>>1)+4(n&1)+8sub+j][q = qlo+ql],
    // already in log2-softmax units (Q pre-scaled).
    float p[4][4];
    if (kv0 + 63 > qlo) {
      const int qrow = qlo + ql;
#pragma unroll
      for (int n = 0; n < 4; ++n) {
        const int kvb = kv0 + 32 * (n >> 1) + 4 * (n & 1) + 8 * sub;
#pragma unroll
        for (int j = 0; j < 4; ++j)
          p[n][j] = (kvb + j > qrow) ? -1e30f : s[n][j];
      }
    } else {
#pragma unroll
      for (int n = 0; n < 4; ++n)
#pragma unroll
        for (int j = 0; j < 4; ++j)
          p[n][j] = s[n][j];
    }

    // in-register online softmax, log2 domain (column q in lanes ql+{0,16,32,48})
    float rmax = p[0][0];
#pragma unroll
    for (int n = 0; n < 4; ++n)
#pragma unroll
      for (int j = 0; j < 4; ++j) rmax = fmaxf(rmax, p[n][j]);
    rmax = fmaxf(rmax, __shfl_xor(rmax, 16));
    rmax = fmaxf(rmax, __shfl_xor(rmax, 32));

    // defer-max (T13): only rescale when the max grew by > 8 (log2)
    if (!__all(rmax <= m_s + 8.0f)) {
      const float mnew = fmaxf(m_s, rmax);
      const float sc = exp2f(m_s - mnew);
      m_s = mnew;
      ol *= sc;
#pragma unroll
      for (int dt = 0; dt < 4; ++dt) o[dt] *= sc;
    }
    const float mcur = m_s;

    bf16x8 pb2[2];  // [kc]: elements 0-3 from tile 2kc, 4-7 from tile 2kc+1
#pragma unroll
    for (int n = 0; n < 4; ++n)
#pragma unroll
      for (int j = 0; j < 4; ++j)
        pb2[n >> 1][(n & 1) * 4 + j] = (bf16)exp2f(p[n][j] - mcur);

    // O^T[d][q] += V^T[d][kv] * P^T[kv][q]; l += 1^T * P (matrix pipe)
    __builtin_amdgcn_s_setprio(1);
#pragma unroll
    for (int kc = 0; kc < 2; ++kc) {
      ol = __builtin_amdgcn_mfma_f32_16x16x32_bf16(ones8, pb2[kc], ol, 0, 0, 0);
#pragma unroll
      for (int dt = 0; dt < 4; ++dt)
        o[dt] = __builtin_amdgcn_mfma_f32_16x16x32_bf16(vf[kc][dt], pb2[kc], o[dt], 0, 0, 0);
    }
    __builtin_amdgcn_s_setprio(0);

    if (f == ntA - 1) {
      // phase A complete: flush and reset the online-softmax state
      FLUSH(q0A);
#pragma unroll
      for (int dt = 0; dt < 4; ++dt) o[dt] = f32x4{};
      ol = f32x4{};
      m_s = -1e30f;
    }
  }

  FLUSH(q0B);
}

// ---------------------------------------------------------------- launch

extern "C" void kernel_launch(void* const* d_in, const int* in_sizes, int n_in,
                              void* d_out, int out_size, void* d_ws, size_t ws_size,
                              hipStream_t stream) {
  const float* x = (const float*)d_in[0];
  const float* Wq = (const float*)d_in[1];
  const float* Wk = (const float*)d_in[2];
  const float* Wv = (const float*)d_in[3];
  const float* Wo = (const float*)d_in[4];
  float* out = (float*)d_out;

  char* ws = (char*)d_ws;
  size_t off = 0;
  auto alloc = [&](size_t bytes) -> void* {
    void* p = ws + off;
    off += (bytes + 255) & ~(size_t)255;
    return p;
  };
  bf16* xb = (bf16*)alloc((size_t)NBT * NE * 2);
  bf16* wqkv_t = (bf16*)alloc((size_t)NQKV * NE * 2);
  bf16* wo_t = (bf16*)alloc((size_t)NE * NE * 2);
  bf16* qkv = (bf16*)alloc((size_t)NBT * NQKV * 2);
  bf16* vtb = (bf16*)alloc((size_t)NB * NHKV * ND * NT * 2);
  bf16* yb = (bf16*)alloc((size_t)NBT * NE * 2);
  float* tab = (float*)alloc((size_t)NT * 64 * 4);

  prep_kernel<<<11520, 256, 0, stream>>>(x, Wq, Wk, Wv, Wo, xb, wqkv_t, wo_t, tab);
  gemm_r3_kernel<bf16, true><<<dim3((NQKV / 128) * (NBT / 128)), 256, 0, stream>>>(
      xb, wqkv_t, qkv, NBT, NQKV, NE, tab, vtb);
  attn_kernel<<<dim3(16 * 64), 256, 0, stream>>>(qkv, vtb, yb);
  gemm_r3_kernel<float, false><<<dim3((NE / 128) * (NBT / 128)), 256, 0, stream>>>(
      yb, wo_t, out, NBT, NE, NE, nullptr, nullptr);
}

// Round 14
// 190.677 us; speedup vs baseline: 1.0933x; 1.0933x over previous
//
#include <hip/hip_runtime.h>
#include <hip/hip_bf16.h>
#include <cstdint>
#include <cstddef>

typedef __bf16 bf16;
typedef __attribute__((ext_vector_type(8))) __bf16 bf16x8;
typedef __attribute__((ext_vector_type(4))) __bf16 bf16x4v;
typedef __attribute__((ext_vector_type(4))) float f32x4;

#define NB 2
#define NT 2048
#define NE 2048
#define NH 32
#define NHKV 8
#define ND 64
#define NBT (NB * NT)
#define NQKV 3072

__device__ __forceinline__ void gload_lds16(const void* g, void* l) {
  __builtin_amdgcn_global_load_lds(
      (const __attribute__((address_space(1))) unsigned int*)g,
      (__attribute__((address_space(3))) unsigned int*)l, 16, 0, 0);
}

// XOR swizzle for 128-byte LDS rows: spreads the 16-way bank conflict.
__device__ __forceinline__ int swz(int row, int byteoff) {
  return (row * 128 + byteoff) ^ ((row & 7) << 4);
}

// ---------------------------------------------------------------- prep kernel
// One fused launch: x->bf16 cvt, rope table, 4 weight transposes.
// Zones by blockIdx.x:  [0,1024) cvt | [1024,1280) table |
// [1280,5376) Wq^T | [5376,6400) Wk^T | [6400,7424) Wv^T | [7424,11520) Wo^T

__global__ __launch_bounds__(256)
void prep_kernel(const float* __restrict__ x, const float* __restrict__ Wq,
                 const float* __restrict__ Wk, const float* __restrict__ Wv,
                 const float* __restrict__ Wo, bf16* __restrict__ xb,
                 bf16* __restrict__ wqkv_t, bf16* __restrict__ wo_t,
                 float* __restrict__ tab) {
  const int bid = blockIdx.x, tid = threadIdx.x;

  if (bid < 1024) {  // x -> bf16, vectorized, grid-stride
    const int n4 = NBT * NE / 4;
    for (int i = bid * 256 + tid; i < n4; i += 1024 * 256) {
      const float4 v = ((const float4*)x)[i];
      bf16x4v o;
      o[0] = (bf16)v.x; o[1] = (bf16)v.y; o[2] = (bf16)v.z; o[3] = (bf16)v.w;
      ((bf16x4v*)xb)[i] = o;
    }
    return;
  }
  if (bid < 1280) {  // rope cos/sin table (65536 entries exactly)
    const int i = (bid - 1024) * 256 + tid;
    const int t = i >> 5, d = i & 31;
    const float inv = expf(-(float)d * 0.28782313662425574f);  // ln(10000)/32
    const float ang = (float)t * inv;
    tab[t * 64 + d] = cosf(ang);
    tab[t * 64 + 32 + d] = sinf(ang);
    return;
  }

  __shared__ float tile[32][33];
  const float* in;
  bf16* outp;
  int ncols, rowoff, gx, sub;
  if (bid < 5376)      { sub = bid - 1280; in = Wq; outp = wqkv_t; ncols = 2048; rowoff = 0;    gx = 64; }
  else if (bid < 6400) { sub = bid - 5376; in = Wk; outp = wqkv_t; ncols = 512;  rowoff = 2048; gx = 16; }
  else if (bid < 7424) { sub = bid - 6400; in = Wv; outp = wqkv_t; ncols = 512;  rowoff = 2560; gx = 16; }
  else                 { sub = bid - 7424; in = Wo; outp = wo_t;   ncols = 2048; rowoff = 0;    gx = 64; }
  const int c0 = (sub % gx) * 32, k0 = (sub / gx) * 32;
  const int tx = tid & 31, ty = tid >> 5;
#pragma unroll
  for (int j = 0; j < 4; ++j)
    tile[ty + j * 8][tx] = in[(size_t)(k0 + ty + j * 8) * ncols + c0 + tx];
  __syncthreads();
#pragma unroll
  for (int j = 0; j < 4; ++j)
    outp[(size_t)(rowoff + c0 + ty + j * 8) * 2048 + k0 + tx] = (bf16)tile[tx][ty + j * 8];
}

// ---------------------------------------------------------------- GEMM (ring-3, never-drain, T2-swizzled)
// C[M][N] = A[M][K] * Bt[N][K]^T ; 128x128 tile, BK=32, 4 waves.
// Ring-3 LDS (48 KB -> 3 blocks/CU TLP) + prefetch distance 2 K-tiles +
// counted vmcnt(4) + ONE raw barrier per K-tile. T2 both-sides swizzle.
// ROPE epilogue: rotate (d,d+32) pairs for q/k heads (cols<2560), fold
// 0.125*log2(e) into Q (cols<2048), and write V panel (cols>=2560)
// TRANSPOSED into vt[b][hk][d][t].

template <typename CT, bool ROPE>
__global__ __launch_bounds__(256, 3)
void gemm_r3_kernel(const bf16* __restrict__ A, const bf16* __restrict__ Bt,
                    CT* __restrict__ C, int M, int N, int K,
                    const float* __restrict__ tab, bf16* __restrict__ vt) {
  __shared__ __align__(16) bf16 As[3][128 * 32];
  __shared__ __align__(16) bf16 Bs[3][128 * 32];
  const int tid = threadIdx.x;
  const int lane = tid & 63, wid = tid >> 6;
  const int wr = wid >> 1, wc = wid & 1;
  const int cpx = (int)gridDim.x >> 3;
  const int swzb = ((int)blockIdx.x & 7) * cpx + ((int)blockIdx.x >> 3);
  const int gx = N >> 7;
  const int bx = swzb % gx, by = swzb / gx;
  const int m0 = by * 128, n0 = bx * 128;
  const int srow = tid >> 2;                              // 0..63 staging row
  const int skoff = 8 * ((tid & 3) ^ ((tid >> 3) & 3));   // T2 source swizzle
  const bf16* ga = A + (size_t)(m0 + srow) * K + skoff;
  const bf16* gb = Bt + (size_t)(n0 + srow) * K + skoff;
  const int fr = lane & 15;
  const int fq = lane >> 4;
  const int fks = 8 * (fq ^ ((fr >> 1) & 3));             // T2 read swizzle
  const int NTK = K >> 5;
  f32x4 acc[4][4] = {};

#define STAGE_T(b, t)                                                   \
  do {                                                                  \
    const int kk = (t) * 32;                                            \
    gload_lds16(ga + kk, &As[b][tid * 8]);                              \
    gload_lds16(ga + kk + (size_t)64 * K, &As[b][2048 + tid * 8]);      \
    gload_lds16(gb + kk, &Bs[b][tid * 8]);                              \
    gload_lds16(gb + kk + (size_t)64 * K, &Bs[b][2048 + tid * 8]);      \
  } while (0)

  STAGE_T(0, 0);
  STAGE_T(1, 1);

  int bc = 0;
  for (int t = 0; t < NTK; ++t) {
    if (t + 1 < NTK) asm volatile("s_waitcnt vmcnt(4)" ::: "memory");
    else             asm volatile("s_waitcnt vmcnt(0)" ::: "memory");
    __builtin_amdgcn_s_barrier();

    bf16x8 af[4], bfr[4];
#pragma unroll
    for (int m = 0; m < 4; ++m)
      af[m] = *(const bf16x8*)&As[bc][(wr * 64 + m * 16 + fr) * 32 + fks];
#pragma unroll
    for (int n = 0; n < 4; ++n)
      bfr[n] = *(const bf16x8*)&Bs[bc][(wc * 64 + n * 16 + fr) * 32 + fks];

    if (t + 2 < NTK) {
      const int pb = (bc + 2 >= 3) ? bc - 1 : bc + 2;
      STAGE_T(pb, t + 2);
    }

    __builtin_amdgcn_s_setprio(1);
#pragma unroll
    for (int m = 0; m < 4; ++m)
#pragma unroll
      for (int n = 0; n < 4; ++n)
        acc[m][n] = __builtin_amdgcn_mfma_f32_16x16x32_bf16(af[m], bfr[n], acc[m][n], 0, 0, 0);
    __builtin_amdgcn_s_setprio(0);
    bc = (bc + 1 == 3) ? 0 : bc + 1;
  }
#undef STAGE_T

  const int colbase = n0 + wc * 64;

  if (ROPE && colbase >= 2560) {
    // V panel: write transposed into vt[b][hk][d][t].
    const int hk = (colbase - 2560) >> 6;
    const int bb = m0 >> 11;
    const int t0 = (m0 & (NT - 1)) + wr * 64 + fq * 4;
    bf16* vtp = vt + (size_t)(bb * NHKV + hk) * 64 * NT;
#pragma unroll
    for (int m = 0; m < 4; ++m) {
#pragma unroll
      for (int n = 0; n < 4; ++n) {
        const int d = n * 16 + fr;
        bf16x4v w;
        w[0] = (bf16)acc[m][n][0];
        w[1] = (bf16)acc[m][n][1];
        w[2] = (bf16)acc[m][n][2];
        w[3] = (bf16)acc[m][n][3];
        *(bf16x4v*)&vtp[(size_t)d * NT + t0 + m * 16] = w;
      }
    }
    return;
  }

  const bool do_rope = ROPE && colbase < 2560;
  const bool do_scale = ROPE && colbase < 2048;
  const float SCALE = 0.18033688011112042f;  // 0.125 * log2(e)
  const int orow0 = m0 + wr * 64 + fq * 4;
  const int ocol0 = colbase + fr;
#pragma unroll
  for (int m = 0; m < 4; ++m) {
#pragma unroll
    for (int j = 0; j < 4; ++j) {
      const int row = orow0 + m * 16 + j;
      float v0 = acc[m][0][j], v1 = acc[m][1][j], v2 = acc[m][2][j], v3 = acc[m][3][j];
      if (do_rope) {
        const int tt = row & (NT - 1);
        const float c0 = tab[tt * 64 + fr],      s0 = tab[tt * 64 + 32 + fr];
        const float c1 = tab[tt * 64 + 16 + fr], s1 = tab[tt * 64 + 48 + fr];
        const float a0 = v0, a2 = v2;
        v0 = a0 * c0 - a2 * s0;
        v2 = a2 * c0 + a0 * s0;
        const float a1 = v1, a3 = v3;
        v1 = a1 * c1 - a3 * s1;
        v3 = a3 * c1 + a1 * s1;
        if (do_scale) { v0 *= SCALE; v1 *= SCALE; v2 *= SCALE; v3 *= SCALE; }
      }
      CT* cp = &C[(size_t)row * N + ocol0];
      cp[0] = (CT)v0; cp[16] = (CT)v1; cp[32] = (CT)v2; cp[48] = (CT)v3;
    }
  }
}

// ---------------------------------------------------------------- attention
// Swapped-operand flash attention (round-12 configuration, measured 77.2us —
// session-best total 191.07us). One block = 128 q rows of one (b,h).
// 4 waves x 32 q rows (2 sets of 16). KVBLK = 64, causal.
// RING-2 K/V LDS (32 KB) with __launch_bounds__(256, 3) — the measured
// no-spill sweet spot (84 VGPR; (256,4)/(256,5) spill 300MB-1.7GB scratch,
// unbounded bloats to 116 VGPR / 91.5us). Per tile: vmcnt(0) (loads issued
// one full tile ago; K/V L2-resident) -> barrier -> STAGE(next into freed
// buffer). Grid 1-D big-first (1024 blocks). K row-permuted in LDS
// (conflict-free kf). Q pre-scaled by 0.125*log2(e) in GEMM1.
// Softmax log2-domain, defer-max (T13), l via MFMA on the matrix pipe.
// NOTE (r13): folding to 64-row q-tiles for load balance regressed to
// 93.8us — halving the q-tile doubles per-tile overhead (staging, barrier,
// kf/vf reads). Do not re-attempt below 128-row granularity.

__global__ __launch_bounds__(256, 3)
void attn_kernel(const bf16* __restrict__ qkv, const bf16* __restrict__ vt,
                 bf16* __restrict__ y) {
  const int bid = blockIdx.x;
  const int qtb = 15 - (bid >> 6);   // big blocks dispatched first
  const int bh = bid & 63;
  const int b = bh >> 5, h = bh & 31, hk = h >> 2;
  const int q0 = qtb * 128;

  __shared__ __align__(16) bf16 Kb[2][4096], Vb[2][4096];

  const int tid = threadIdx.x;
  const int lane = tid & 63, wid = tid >> 6;
  const int ql = lane & 15;
  const int sub = lane >> 4;

  const int st_r = tid >> 3;
  const int kperm = 4 * (st_r >> 4) + 8 * ((st_r >> 2) & 3) + (st_r & 3);
  const int csw = ((tid & 7) ^ (st_r & 7)) * 8;
  const bf16* kgbase = qkv + (size_t)(b * NT + kperm) * NQKV + 2048 + hk * 64 + csw;
  const bf16* vgbase = vt + ((size_t)(b * NHKV + hk) * 64 + st_r) * NT + csw;

  auto STAGE = [&](int buf, int kv0) {
    const bf16* kg = kgbase + (size_t)kv0 * NQKV;
    gload_lds16(kg, Kb[buf] + tid * 8);
    gload_lds16(kg + (size_t)32 * NQKV, Kb[buf] + 2048 + tid * 8);
    const bf16* vg = vgbase + kv0;
    gload_lds16(vg, Vb[buf] + tid * 8);
    gload_lds16(vg + 32 * NT, Vb[buf] + 2048 + tid * 8);
  };

  // Q fragments (post-RoPE, pre-scaled): B-operand, col=q=ql, k=d=sub*8+j
  bf16x8 qf[2][2];
#pragma unroll
  for (int set = 0; set < 2; ++set) {
    const bf16* qp = qkv + (size_t)(b * NT + q0 + wid * 32 + set * 16 + ql) * NQKV + h * 64 + sub * 8;
    qf[set][0] = *(const bf16x8*)qp;
    qf[set][1] = *(const bf16x8*)(qp + 32);
  }

  bf16x8 ones8;
#pragma unroll
  for (int i = 0; i < 8; ++i) ones8[i] = (bf16)1.0f;

  f32x4 o[2][4] = {};
  f32x4 ol[2] = {};               // l accumulator via MFMA (all 4 elems equal)
  float m_s[2] = {-1e30f, -1e30f};

  const int ntiles = 2 * qtb + 2;
  STAGE(0, 0);

  for (int it = 0; it < ntiles; ++it) {
    const int kv0 = it * 64;
    const int bc = it & 1;
    asm volatile("s_waitcnt vmcnt(0)" ::: "memory");
    __builtin_amdgcn_s_barrier();
    if (it + 1 < ntiles) STAGE(bc ^ 1, kv0 + 64);

    if (kv0 <= q0 + wid * 32 + 47) {  // at least one set active for this wave
      bf16x8 kf[4][2];
#pragma unroll
      for (int n = 0; n < 4; ++n)
#pragma unroll
        for (int c = 0; c < 2; ++c)
          kf[n][c] = *(const bf16x8*)((const char*)Kb[bc] + swz(n * 16 + ql, c * 64 + sub * 16));
      bf16x8 vf[2][4];
#pragma unroll
      for (int kc = 0; kc < 2; ++kc)
#pragma unroll
        for (int dt = 0; dt < 4; ++dt)
          vf[kc][dt] = *(const bf16x8*)((const char*)Vb[bc] + swz(dt * 16 + ql, kc * 64 + sub * 16));

#pragma unroll
      for (int set = 0; set < 2; ++set) {
        const int qlo = q0 + wid * 32 + set * 16;
        if (kv0 > qlo + 15) continue;  // fully masked for this set

        f32x4 s[4] = {};
        __builtin_amdgcn_s_setprio(1);
#pragma unroll
        for (int n = 0; n < 4; ++n) {
          s[n] = __builtin_amdgcn_mfma_f32_16x16x32_bf16(kf[n][0], qf[set][0], s[n], 0, 0, 0);
          s[n] = __builtin_amdgcn_mfma_f32_16x16x32_bf16(kf[n][1], qf[set][1], s[n], 0, 0, 0);
        }
        __builtin_amdgcn_s_setprio(0);

        // lane holds S^T[kv = kv0+32(n>>1)+4(n&1)+8sub+j][q = qlo+ql],
        // already in log2-softmax units (Q pre-scaled).
        float p[4][4];
        if (kv0 + 63 > qlo) {
          const int qrow = qlo + ql;
#pragma unroll
          for (int n = 0; n < 4; ++n) {
            const int kvb = kv0 + 32 * (n >> 1) + 4 * (n & 1) + 8 * sub;
#pragma unroll
            for (int j = 0; j < 4; ++j)
              p[n][j] = (kvb + j > qrow) ? -1e30f : s[n][j];
          }
        } else {
#pragma unroll
          for (int n = 0; n < 4; ++n)
#pragma unroll
            for (int j = 0; j < 4; ++j)
              p[n][j] = s[n][j];
        }

        // in-register online softmax, log2 domain (column q lives in lanes
        // ql+{0,16,32,48})
        float rmax = p[0][0];
#pragma unroll
        for (int n = 0; n < 4; ++n)
#pragma unroll
          for (int j = 0; j < 4; ++j) rmax = fmaxf(rmax, p[n][j]);
        rmax = fmaxf(rmax, __shfl_xor(rmax, 16));
        rmax = fmaxf(rmax, __shfl_xor(rmax, 32));

        // defer-max (T13): only rescale when the max grew by > 8 (log2)
        if (!__all(rmax <= m_s[set] + 8.0f)) {
          const float mnew = fmaxf(m_s[set], rmax);
          const float sc = exp2f(m_s[set] - mnew);
          m_s[set] = mnew;
          ol[set] *= sc;
#pragma unroll
          for (int dt = 0; dt < 4; ++dt) o[set][dt] *= sc;
        }
        const float mcur = m_s[set];

        bf16x8 pb2[2];  // [kc]: elements 0-3 from tile 2kc, 4-7 from tile 2kc+1
#pragma unroll
        for (int n = 0; n < 4; ++n)
#pragma unroll
          for (int j = 0; j < 4; ++j)
            pb2[n >> 1][(n & 1) * 4 + j] = (bf16)exp2f(p[n][j] - mcur);

        // O^T[d][q] += V^T[d][kv] * P^T[kv][q]; l += 1^T * P (matrix pipe)
        __builtin_amdgcn_s_setprio(1);
#pragma unroll
        for (int kc = 0; kc < 2; ++kc) {
          ol[set] = __builtin_amdgcn_mfma_f32_16x16x32_bf16(ones8, pb2[kc], ol[set], 0, 0, 0);
#pragma unroll
          for (int dt = 0; dt < 4; ++dt)
            o[set][dt] = __builtin_amdgcn_mfma_f32_16x16x32_bf16(vf[kc][dt], pb2[kc], o[set][dt], 0, 0, 0);
        }
        __builtin_amdgcn_s_setprio(0);
      }
    }
  }

  // epilogue: o[set][dt][j] = O[q=qlo+ql][d=dt*16+sub*4+j]
#pragma unroll
  for (int set = 0; set < 2; ++set) {
    const float inv = 1.0f / ol[set][0];
    bf16* yp = y + (size_t)(b * NT + q0 + wid * 32 + set * 16 + ql) * NE + h * 64 + sub * 4;
#pragma unroll
    for (int dt = 0; dt < 4; ++dt) {
      bf16x4v w;
      w[0] = (bf16)(o[set][dt][0] * inv);
      w[1] = (bf16)(o[set][dt][1] * inv);
      w[2] = (bf16)(o[set][dt][2] * inv);
      w[3] = (bf16)(o[set][dt][3] * inv);
      *(bf16x4v*)(yp + dt * 16) = w;
    }
  }
}

// ---------------------------------------------------------------- launch

extern "C" void kernel_launch(void* const* d_in, const int* in_sizes, int n_in,
                              void* d_out, int out_size, void* d_ws, size_t ws_size,
                              hipStream_t stream) {
  const float* x = (const float*)d_in[0];
  const float* Wq = (const float*)d_in[1];
  const float* Wk = (const float*)d_in[2];
  const float* Wv = (const float*)d_in[3];
  const float* Wo = (const float*)d_in[4];
  float* out = (float*)d_out;

  char* ws = (char*)d_ws;
  size_t off = 0;
  auto alloc = [&](size_t bytes) -> void* {
    void* p = ws + off;
    off += (bytes + 255) & ~(size_t)255;
    return p;
  };
  bf16* xb = (bf16*)alloc((size_t)NBT * NE * 2);
  bf16* wqkv_t = (bf16*)alloc((size_t)NQKV * NE * 2);
  bf16* wo_t = (bf16*)alloc((size_t)NE * NE * 2);
  bf16* qkv = (bf16*)alloc((size_t)NBT * NQKV * 2);
  bf16* vtb = (bf16*)alloc((size_t)NB * NHKV * ND * NT * 2);
  bf16* yb = (bf16*)alloc((size_t)NBT * NE * 2);
  float* tab = (float*)alloc((size_t)NT * 64 * 4);

  prep_kernel<<<11520, 256, 0, stream>>>(x, Wq, Wk, Wv, Wo, xb, wqkv_t, wo_t, tab);
  gemm_r3_kernel<bf16, true><<<dim3((NQKV / 128) * (NBT / 128)), 256, 0, stream>>>(
      xb, wqkv_t, qkv, NBT, NQKV, NE, tab, vtb);
  attn_kernel<<<dim3(NT / 128 * 64), 256, 0, stream>>>(qkv, vtb, yb);
  gemm_r3_kernel<float, false><<<dim3((NE / 128) * (NBT / 128)), 256, 0, stream>>>(
      yb, wo_t, out, NBT, NE, NE, nullptr, nullptr);
}

// Round 15
// 187.108 us; speedup vs baseline: 1.1141x; 1.0191x over previous
//
#include <hip/hip_runtime.h>
#include <hip/hip_bf16.h>
#include <cstdint>
#include <cstddef>

typedef __bf16 bf16;
typedef __attribute__((ext_vector_type(8))) __bf16 bf16x8;
typedef __attribute__((ext_vector_type(4))) __bf16 bf16x4v;
typedef __attribute__((ext_vector_type(4))) float f32x4;

#define NB 2
#define NT 2048
#define NE 2048
#define NH 32
#define NHKV 8
#define ND 64
#define NBT (NB * NT)
#define NQKV 3072

__device__ __forceinline__ void gload_lds16(const void* g, void* l) {
  __builtin_amdgcn_global_load_lds(
      (const __attribute__((address_space(1))) unsigned int*)g,
      (__attribute__((address_space(3))) unsigned int*)l, 16, 0, 0);
}

// XOR swizzle for 128-byte LDS rows: spreads the 16-way bank conflict.
__device__ __forceinline__ int swz(int row, int byteoff) {
  return (row * 128 + byteoff) ^ ((row & 7) << 4);
}

// ---------------------------------------------------------------- prep kernel
// One fused launch: x->bf16 cvt, rope table, 4 weight transposes.
// Zones by blockIdx.x:  [0,1024) cvt | [1024,1280) table |
// [1280,5376) Wq^T | [5376,6400) Wk^T | [6400,7424) Wv^T | [7424,11520) Wo^T

__global__ __launch_bounds__(256)
void prep_kernel(const float* __restrict__ x, const float* __restrict__ Wq,
                 const float* __restrict__ Wk, const float* __restrict__ Wv,
                 const float* __restrict__ Wo, bf16* __restrict__ xb,
                 bf16* __restrict__ wqkv_t, bf16* __restrict__ wo_t,
                 float* __restrict__ tab) {
  const int bid = blockIdx.x, tid = threadIdx.x;

  if (bid < 1024) {  // x -> bf16, vectorized, grid-stride
    const int n4 = NBT * NE / 4;
    for (int i = bid * 256 + tid; i < n4; i += 1024 * 256) {
      const float4 v = ((const float4*)x)[i];
      bf16x4v o;
      o[0] = (bf16)v.x; o[1] = (bf16)v.y; o[2] = (bf16)v.z; o[3] = (bf16)v.w;
      ((bf16x4v*)xb)[i] = o;
    }
    return;
  }
  if (bid < 1280) {  // rope cos/sin table (65536 entries exactly)
    const int i = (bid - 1024) * 256 + tid;
    const int t = i >> 5, d = i & 31;
    const float inv = expf(-(float)d * 0.28782313662425574f);  // ln(10000)/32
    const float ang = (float)t * inv;
    tab[t * 64 + d] = cosf(ang);
    tab[t * 64 + 32 + d] = sinf(ang);
    return;
  }

  __shared__ float tile[32][33];
  const float* in;
  bf16* outp;
  int ncols, rowoff, gx, sub;
  if (bid < 5376)      { sub = bid - 1280; in = Wq; outp = wqkv_t; ncols = 2048; rowoff = 0;    gx = 64; }
  else if (bid < 6400) { sub = bid - 5376; in = Wk; outp = wqkv_t; ncols = 512;  rowoff = 2048; gx = 16; }
  else if (bid < 7424) { sub = bid - 6400; in = Wv; outp = wqkv_t; ncols = 512;  rowoff = 2560; gx = 16; }
  else                 { sub = bid - 7424; in = Wo; outp = wo_t;   ncols = 2048; rowoff = 0;    gx = 64; }
  const int c0 = (sub % gx) * 32, k0 = (sub / gx) * 32;
  const int tx = tid & 31, ty = tid >> 5;
#pragma unroll
  for (int j = 0; j < 4; ++j)
    tile[ty + j * 8][tx] = in[(size_t)(k0 + ty + j * 8) * ncols + c0 + tx];
  __syncthreads();
#pragma unroll
  for (int j = 0; j < 4; ++j)
    outp[(size_t)(rowoff + c0 + ty + j * 8) * 2048 + k0 + tx] = (bf16)tile[tx][ty + j * 8];
}

// ---------------------------------------------------------------- GEMM (ring-3, never-drain, T2-swizzled)
// C[M][N] = A[M][K] * Bt[N][K]^T ; 128x128 tile, BK=32, 4 waves.
// Ring-3 LDS (48 KB -> 3 blocks/CU TLP) + prefetch distance 2 K-tiles +
// counted vmcnt(4) + ONE raw barrier per K-tile. T2 both-sides swizzle.
// ROPE epilogue: rotate (d,d+32) pairs for q/k heads (cols<2560), fold
// 0.125*log2(e) into Q (cols<2048), and write V panel (cols>=2560)
// TRANSPOSED into vt[b][hk][d][t].

template <typename CT, bool ROPE>
__global__ __launch_bounds__(256, 3)
void gemm_r3_kernel(const bf16* __restrict__ A, const bf16* __restrict__ Bt,
                    CT* __restrict__ C, int M, int N, int K,
                    const float* __restrict__ tab, bf16* __restrict__ vt) {
  __shared__ __align__(16) bf16 As[3][128 * 32];
  __shared__ __align__(16) bf16 Bs[3][128 * 32];
  const int tid = threadIdx.x;
  const int lane = tid & 63, wid = tid >> 6;
  const int wr = wid >> 1, wc = wid & 1;
  const int cpx = (int)gridDim.x >> 3;
  const int swzb = ((int)blockIdx.x & 7) * cpx + ((int)blockIdx.x >> 3);
  const int gx = N >> 7;
  const int bx = swzb % gx, by = swzb / gx;
  const int m0 = by * 128, n0 = bx * 128;
  const int srow = tid >> 2;                              // 0..63 staging row
  const int skoff = 8 * ((tid & 3) ^ ((tid >> 3) & 3));   // T2 source swizzle
  const bf16* ga = A + (size_t)(m0 + srow) * K + skoff;
  const bf16* gb = Bt + (size_t)(n0 + srow) * K + skoff;
  const int fr = lane & 15;
  const int fq = lane >> 4;
  const int fks = 8 * (fq ^ ((fr >> 1) & 3));             // T2 read swizzle
  const int NTK = K >> 5;
  f32x4 acc[4][4] = {};

#define STAGE_T(b, t)                                                   \
  do {                                                                  \
    const int kk = (t) * 32;                                            \
    gload_lds16(ga + kk, &As[b][tid * 8]);                              \
    gload_lds16(ga + kk + (size_t)64 * K, &As[b][2048 + tid * 8]);      \
    gload_lds16(gb + kk, &Bs[b][tid * 8]);                              \
    gload_lds16(gb + kk + (size_t)64 * K, &Bs[b][2048 + tid * 8]);      \
  } while (0)

  STAGE_T(0, 0);
  STAGE_T(1, 1);

  int bc = 0;
  for (int t = 0; t < NTK; ++t) {
    if (t + 1 < NTK) asm volatile("s_waitcnt vmcnt(4)" ::: "memory");
    else             asm volatile("s_waitcnt vmcnt(0)" ::: "memory");
    __builtin_amdgcn_s_barrier();

    bf16x8 af[4], bfr[4];
#pragma unroll
    for (int m = 0; m < 4; ++m)
      af[m] = *(const bf16x8*)&As[bc][(wr * 64 + m * 16 + fr) * 32 + fks];
#pragma unroll
    for (int n = 0; n < 4; ++n)
      bfr[n] = *(const bf16x8*)&Bs[bc][(wc * 64 + n * 16 + fr) * 32 + fks];

    if (t + 2 < NTK) {
      const int pb = (bc + 2 >= 3) ? bc - 1 : bc + 2;
      STAGE_T(pb, t + 2);
    }

    __builtin_amdgcn_s_setprio(1);
#pragma unroll
    for (int m = 0; m < 4; ++m)
#pragma unroll
      for (int n = 0; n < 4; ++n)
        acc[m][n] = __builtin_amdgcn_mfma_f32_16x16x32_bf16(af[m], bfr[n], acc[m][n], 0, 0, 0);
    __builtin_amdgcn_s_setprio(0);
    bc = (bc + 1 == 3) ? 0 : bc + 1;
  }
#undef STAGE_T

  const int colbase = n0 + wc * 64;

  if (ROPE && colbase >= 2560) {
    // V panel: write transposed into vt[b][hk][d][t].
    const int hk = (colbase - 2560) >> 6;
    const int bb = m0 >> 11;
    const int t0 = (m0 & (NT - 1)) + wr * 64 + fq * 4;
    bf16* vtp = vt + (size_t)(bb * NHKV + hk) * 64 * NT;
#pragma unroll
    for (int m = 0; m < 4; ++m) {
#pragma unroll
      for (int n = 0; n < 4; ++n) {
        const int d = n * 16 + fr;
        bf16x4v w;
        w[0] = (bf16)acc[m][n][0];
        w[1] = (bf16)acc[m][n][1];
        w[2] = (bf16)acc[m][n][2];
        w[3] = (bf16)acc[m][n][3];
        *(bf16x4v*)&vtp[(size_t)d * NT + t0 + m * 16] = w;
      }
    }
    return;
  }

  const bool do_rope = ROPE && colbase < 2560;
  const bool do_scale = ROPE && colbase < 2048;
  const float SCALE = 0.18033688011112042f;  // 0.125 * log2(e)
  const int orow0 = m0 + wr * 64 + fq * 4;
  const int ocol0 = colbase + fr;
#pragma unroll
  for (int m = 0; m < 4; ++m) {
#pragma unroll
    for (int j = 0; j < 4; ++j) {
      const int row = orow0 + m * 16 + j;
      float v0 = acc[m][0][j], v1 = acc[m][1][j], v2 = acc[m][2][j], v3 = acc[m][3][j];
      if (do_rope) {
        const int tt = row & (NT - 1);
        const float c0 = tab[tt * 64 + fr],      s0 = tab[tt * 64 + 32 + fr];
        const float c1 = tab[tt * 64 + 16 + fr], s1 = tab[tt * 64 + 48 + fr];
        const float a0 = v0, a2 = v2;
        v0 = a0 * c0 - a2 * s0;
        v2 = a2 * c0 + a0 * s0;
        const float a1 = v1, a3 = v3;
        v1 = a1 * c1 - a3 * s1;
        v3 = a3 * c1 + a1 * s1;
        if (do_scale) { v0 *= SCALE; v1 *= SCALE; v2 *= SCALE; v3 *= SCALE; }
      }
      CT* cp = &C[(size_t)row * N + ocol0];
      cp[0] = (CT)v0; cp[16] = (CT)v1; cp[32] = (CT)v2; cp[48] = (CT)v3;
    }
  }
}

// ---------------------------------------------------------------- attention
// Swapped-operand flash attention (r12 structure, 77.4us) + SKIP-SHFL
// DEFER-MAX: the per-lane partial max suffices for the defer check
// (each lane's partial <= its column max; colmax = max of 4 partials, so
// __all(partial <= m+8) <=> all colmaxes <= m+8). The 2 cross-lane
// ds_bpermutes (~100-150cy serial latency) move into the RARE slow path
// (first tile + max growth). One block = 128 q rows of one (b,h).
// 4 waves x 32 q rows (2 sets of 16). KVBLK = 64, causal. RING-2 K/V LDS
// (32 KB), __launch_bounds__(256,3) — measured no-spill sweet spot
// (84 VGPR; (256,4)/(256,5) spill; unbounded bloats to 116 VGPR/91.5us).
// Per tile: vmcnt(0) -> barrier -> STAGE(next into freed buffer).
// Grid 1-D big-first. K row-permuted in LDS (conflict-free kf).
// Q pre-scaled by 0.125*log2(e) in GEMM1. Softmax log2-domain,
// l via MFMA on the matrix pipe.
// NOTE (r13): 64-row q-tiles regressed (93.8us) — per-tile overhead
// doubles. NOTE (r14 audit): 8-phase 256" GEMM fill-rate and ring-4
// pairing both compute neutral-to-worse at these shapes.

__global__ __launch_bounds__(256, 3)
void attn_kernel(const bf16* __restrict__ qkv, const bf16* __restrict__ vt,
                 bf16* __restrict__ y) {
  const int bid = blockIdx.x;
  const int qtb = 15 - (bid >> 6);   // big blocks dispatched first
  const int bh = bid & 63;
  const int b = bh >> 5, h = bh & 31, hk = h >> 2;
  const int q0 = qtb * 128;

  __shared__ __align__(16) bf16 Kb[2][4096], Vb[2][4096];

  const int tid = threadIdx.x;
  const int lane = tid & 63, wid = tid >> 6;
  const int ql = lane & 15;
  const int sub = lane >> 4;

  const int st_r = tid >> 3;
  const int kperm = 4 * (st_r >> 4) + 8 * ((st_r >> 2) & 3) + (st_r & 3);
  const int csw = ((tid & 7) ^ (st_r & 7)) * 8;
  const bf16* kgbase = qkv + (size_t)(b * NT + kperm) * NQKV + 2048 + hk * 64 + csw;
  const bf16* vgbase = vt + ((size_t)(b * NHKV + hk) * 64 + st_r) * NT + csw;

  auto STAGE = [&](int buf, int kv0) {
    const bf16* kg = kgbase + (size_t)kv0 * NQKV;
    gload_lds16(kg, Kb[buf] + tid * 8);
    gload_lds16(kg + (size_t)32 * NQKV, Kb[buf] + 2048 + tid * 8);
    const bf16* vg = vgbase + kv0;
    gload_lds16(vg, Vb[buf] + tid * 8);
    gload_lds16(vg + 32 * NT, Vb[buf] + 2048 + tid * 8);
  };

  // Q fragments (post-RoPE, pre-scaled): B-operand, col=q=ql, k=d=sub*8+j
  bf16x8 qf[2][2];
#pragma unroll
  for (int set = 0; set < 2; ++set) {
    const bf16* qp = qkv + (size_t)(b * NT + q0 + wid * 32 + set * 16 + ql) * NQKV + h * 64 + sub * 8;
    qf[set][0] = *(const bf16x8*)qp;
    qf[set][1] = *(const bf16x8*)(qp + 32);
  }

  bf16x8 ones8;
#pragma unroll
  for (int i = 0; i < 8; ++i) ones8[i] = (bf16)1.0f;

  f32x4 o[2][4] = {};
  f32x4 ol[2] = {};               // l accumulator via MFMA (all 4 elems equal)
  float m_s[2] = {-1e30f, -1e30f};

  const int ntiles = 2 * qtb + 2;
  STAGE(0, 0);

  for (int it = 0; it < ntiles; ++it) {
    const int kv0 = it * 64;
    const int bc = it & 1;
    asm volatile("s_waitcnt vmcnt(0)" ::: "memory");
    __builtin_amdgcn_s_barrier();
    if (it + 1 < ntiles) STAGE(bc ^ 1, kv0 + 64);

    if (kv0 <= q0 + wid * 32 + 47) {  // at least one set active for this wave
      bf16x8 kf[4][2];
#pragma unroll
      for (int n = 0; n < 4; ++n)
#pragma unroll
        for (int c = 0; c < 2; ++c)
          kf[n][c] = *(const bf16x8*)((const char*)Kb[bc] + swz(n * 16 + ql, c * 64 + sub * 16));
      bf16x8 vf[2][4];
#pragma unroll
      for (int kc = 0; kc < 2; ++kc)
#pragma unroll
        for (int dt = 0; dt < 4; ++dt)
          vf[kc][dt] = *(const bf16x8*)((const char*)Vb[bc] + swz(dt * 16 + ql, kc * 64 + sub * 16));

#pragma unroll
      for (int set = 0; set < 2; ++set) {
        const int qlo = q0 + wid * 32 + set * 16;
        if (kv0 > qlo + 15) continue;  // fully masked for this set

        f32x4 s[4] = {};
        __builtin_amdgcn_s_setprio(1);
#pragma unroll
        for (int n = 0; n < 4; ++n) {
          s[n] = __builtin_amdgcn_mfma_f32_16x16x32_bf16(kf[n][0], qf[set][0], s[n], 0, 0, 0);
          s[n] = __builtin_amdgcn_mfma_f32_16x16x32_bf16(kf[n][1], qf[set][1], s[n], 0, 0, 0);
        }
        __builtin_amdgcn_s_setprio(0);

        // lane holds S^T[kv = kv0+32(n>>1)+4(n&1)+8sub+j][q = qlo+ql],
        // already in log2-softmax units (Q pre-scaled).
        float p[4][4];
        if (kv0 + 63 > qlo) {
          const int qrow = qlo + ql;
#pragma unroll
          for (int n = 0; n < 4; ++n) {
            const int kvb = kv0 + 32 * (n >> 1) + 4 * (n & 1) + 8 * sub;
#pragma unroll
            for (int j = 0; j < 4; ++j)
              p[n][j] = (kvb + j > qrow) ? -1e30f : s[n][j];
          }
        } else {
#pragma unroll
          for (int n = 0; n < 4; ++n)
#pragma unroll
            for (int j = 0; j < 4; ++j)
              p[n][j] = s[n][j];
        }

        // per-lane partial max only (no cross-lane shfl in the fast path)
        float pmax = p[0][0];
#pragma unroll
        for (int n = 0; n < 4; ++n)
#pragma unroll
          for (int j = 0; j < 4; ++j) pmax = fmaxf(pmax, p[n][j]);

        // defer-max (T13) with skip-shfl check: __all over per-lane partials
        // is equivalent to checking every column max (colmax = max of the
        // 4 partials in lanes ql+{0,16,32,48}).
        if (!__all(pmax <= m_s[set] + 8.0f)) {
          // slow path (rare): build the true column max, rescale.
          float rmax = pmax;
          rmax = fmaxf(rmax, __shfl_xor(rmax, 16));
          rmax = fmaxf(rmax, __shfl_xor(rmax, 32));
          const float mnew = fmaxf(m_s[set], rmax);
          const float sc = exp2f(m_s[set] - mnew);
          m_s[set] = mnew;
          ol[set] *= sc;
#pragma unroll
          for (int dt = 0; dt < 4; ++dt) o[set][dt] *= sc;
        }
        const float mcur = m_s[set];

        bf16x8 pb2[2];  // [kc]: elements 0-3 from tile 2kc, 4-7 from tile 2kc+1
#pragma unroll
        for (int n = 0; n < 4; ++n)
#pragma unroll
          for (int j = 0; j < 4; ++j)
            pb2[n >> 1][(n & 1) * 4 + j] = (bf16)exp2f(p[n][j] - mcur);

        // O^T[d][q] += V^T[d][kv] * P^T[kv][q]; l += 1^T * P (matrix pipe)
        __builtin_amdgcn_s_setprio(1);
#pragma unroll
        for (int kc = 0; kc < 2; ++kc) {
          ol[set] = __builtin_amdgcn_mfma_f32_16x16x32_bf16(ones8, pb2[kc], ol[set], 0, 0, 0);
#pragma unroll
          for (int dt = 0; dt < 4; ++dt)
            o[set][dt] = __builtin_amdgcn_mfma_f32_16x16x32_bf16(vf[kc][dt], pb2[kc], o[set][dt], 0, 0, 0);
        }
        __builtin_amdgcn_s_setprio(0);
      }
    }
  }

  // epilogue: o[set][dt][j] = O[q=qlo+ql][d=dt*16+sub*4+j]
#pragma unroll
  for (int set = 0; set < 2; ++set) {
    const float inv = 1.0f / ol[set][0];
    bf16* yp = y + (size_t)(b * NT + q0 + wid * 32 + set * 16 + ql) * NE + h * 64 + sub * 4;
#pragma unroll
    for (int dt = 0; dt < 4; ++dt) {
      bf16x4v w;
      w[0] = (bf16)(o[set][dt][0] * inv);
      w[1] = (bf16)(o[set][dt][1] * inv);
      w[2] = (bf16)(o[set][dt][2] * inv);
      w[3] = (bf16)(o[set][dt][3] * inv);
      *(bf16x4v*)(yp + dt * 16) = w;
    }
  }
}

// ---------------------------------------------------------------- launch

extern "C" void kernel_launch(void* const* d_in, const int* in_sizes, int n_in,
                              void* d_out, int out_size, void* d_ws, size_t ws_size,
                              hipStream_t stream) {
  const float* x = (const float*)d_in[0];
  const float* Wq = (const float*)d_in[1];
  const float* Wk = (const float*)d_in[2];
  const float* Wv = (const float*)d_in[3];
  const float* Wo = (const float*)d_in[4];
  float* out = (float*)d_out;

  char* ws = (char*)d_ws;
  size_t off = 0;
  auto alloc = [&](size_t bytes) -> void* {
    void* p = ws + off;
    off += (bytes + 255) & ~(size_t)255;
    return p;
  };
  bf16* xb = (bf16*)alloc((size_t)NBT * NE * 2);
  bf16* wqkv_t = (bf16*)alloc((size_t)NQKV * NE * 2);
  bf16* wo_t = (bf16*)alloc((size_t)NE * NE * 2);
  bf16* qkv = (bf16*)alloc((size_t)NBT * NQKV * 2);
  bf16* vtb = (bf16*)alloc((size_t)NB * NHKV * ND * NT * 2);
  bf16* yb = (bf16*)alloc((size_t)NBT * NE * 2);
  float* tab = (float*)alloc((size_t)NT * 64 * 4);

  prep_kernel<<<11520, 256, 0, stream>>>(x, Wq, Wk, Wv, Wo, xb, wqkv_t, wo_t, tab);
  gemm_r3_kernel<bf16, true><<<dim3((NQKV / 128) * (NBT / 128)), 256, 0, stream>>>(
      xb, wqkv_t, qkv, NBT, NQKV, NE, tab, vtb);
  attn_kernel<<<dim3(NT / 128 * 64), 256, 0, stream>>>(qkv, vtb, yb);
  gemm_r3_kernel<float, false><<<dim3((NE / 128) * (NBT / 128)), 256, 0, stream>>>(
      yb, wo_t, out, NBT, NE, NE, nullptr, nullptr);
}